// Round 1
// baseline (180.003 us; speedup 1.0000x reference)
//
#include <hip/hip_runtime.h>
#include <math.h>

#define DD 160
#define HH 160
#define WW 160
#define NB 2
#define NEL (NB*DD*HH*WW)   // 8,192,000 elements per channel
#define TX 32
#define TY 16
#define ZCHUNK 32
#define NCOL (NB*HH*WW)     // 51200 columns
#define NCHUNK (DD/ZCHUNK)  // 5
#define S2_BLOCKS ((NCOL*NCHUNK)/256)  // 1000

struct G7 { float g[7]; };

// Stage 1: per z-slice, fused W-conv + H-conv in LDS for 5 channels
// (p, t, p^2, t^2, p*t). Writes channel-major intermediate to ws.
__global__ __launch_bounds__(512) void ssim_stage1(
        const float* __restrict__ p, const float* __restrict__ t,
        float* __restrict__ out, G7 gw) {
    const int zb = blockIdx.z;              // n*DD + z
    const int x0 = blockIdx.x * TX;
    const int y0 = blockIdx.y * TY;

    __shared__ float sp[TY + 6][TX + 6];
    __shared__ float st[TY + 6][TX + 6];
    __shared__ float c[5][TY + 6][TX];

    const int tid = threadIdx.y * TX + threadIdx.x;   // 0..511
    const float* pbase = p + (size_t)zb * (HH * WW);
    const float* tbase = t + (size_t)zb * (HH * WW);

    // Load halo tile (zero padding outside the slice)
    for (int i = tid; i < (TY + 6) * (TX + 6); i += 512) {
        int r = i / (TX + 6), cc = i % (TX + 6);
        int gy = y0 + r - 3, gx = x0 + cc - 3;
        float vp = 0.f, vt = 0.f;
        if (gy >= 0 && gy < HH && gx >= 0 && gx < WW) {
            vp = pbase[gy * WW + gx];
            vt = tbase[gy * WW + gx];
        }
        sp[r][cc] = vp; st[r][cc] = vt;
    }
    __syncthreads();

    // X-conv for all 5 channels, over (TY+6) rows x TX cols
    for (int i = tid; i < (TY + 6) * TX; i += 512) {
        int r = i / TX, j = i % TX;
        float s0 = 0.f, s1 = 0.f, s2 = 0.f, s3 = 0.f, s4 = 0.f;
#pragma unroll
        for (int k = 0; k < 7; ++k) {
            float wgt = gw.g[k];
            float a = sp[r][j + k], b = st[r][j + k];
            s0 += wgt * a;
            s1 += wgt * b;
            s2 += wgt * a * a;
            s3 += wgt * b * b;
            s4 += wgt * a * b;
        }
        c[0][r][j] = s0; c[1][r][j] = s1; c[2][r][j] = s2;
        c[3][r][j] = s3; c[4][r][j] = s4;
    }
    __syncthreads();

    // Y-conv, one output voxel per thread (grid exactly tiles 160x160)
    const int ty = threadIdx.y, tx = threadIdx.x;
    float r0 = 0.f, r1 = 0.f, r2 = 0.f, r3 = 0.f, r4 = 0.f;
#pragma unroll
    for (int k = 0; k < 7; ++k) {
        float wgt = gw.g[k];
        r0 += wgt * c[0][ty + k][tx];
        r1 += wgt * c[1][ty + k][tx];
        r2 += wgt * c[2][ty + k][tx];
        r3 += wgt * c[3][ty + k][tx];
        r4 += wgt * c[4][ty + k][tx];
    }
    size_t o = (size_t)zb * (HH * WW) + (size_t)(y0 + ty) * WW + (x0 + tx);
    out[o]                    = r0;
    out[o + (size_t)NEL]      = r1;
    out[o + 2ul * NEL]        = r2;
    out[o + 3ul * NEL]        = r3;
    out[o + 4ul * NEL]        = r4;
}

// Stage 2: D-conv via register shift window + fused SSIM map + block reduce.
// Each thread owns one (n,y,x) column for one z-chunk of 32 outputs.
__global__ __launch_bounds__(256) void ssim_stage2(
        const float* __restrict__ c, float* __restrict__ partial, G7 gw) {
    const int gid = blockIdx.x * 256 + threadIdx.x;
    const int col = gid % NCOL;          // consecutive threads -> consecutive (y*W+x)
    const int chunk = gid / NCOL;
    const int n = col / (HH * WW);
    const int yx = col % (HH * WW);
    const int zs = chunk * ZCHUNK;

    const float* base = c + (size_t)n * DD * HH * WW + yx;

    float wnd[5][7];
#pragma unroll
    for (int ch = 0; ch < 5; ++ch)
#pragma unroll
        for (int k = 0; k < 7; ++k) wnd[ch][k] = 0.f;

    const float C1v = 1e-4f, C2v = 9e-4f;
    float acc = 0.f;

    for (int z = zs - 3; z < zs + ZCHUNK + 3; ++z) {
        float v[5];
        if (z >= 0 && z < DD) {
            size_t off = (size_t)z * (HH * WW);
#pragma unroll
            for (int ch = 0; ch < 5; ++ch)
                v[ch] = base[off + (size_t)ch * NEL];
        } else {
#pragma unroll
            for (int ch = 0; ch < 5; ++ch) v[ch] = 0.f;
        }
#pragma unroll
        for (int ch = 0; ch < 5; ++ch) {
#pragma unroll
            for (int k = 0; k < 6; ++k) wnd[ch][k] = wnd[ch][k + 1];
            wnd[ch][6] = v[ch];
        }
        if (z >= zs + 3) {   // output zo = z-3 in [zs, zs+ZCHUNK)
            float m[5];
#pragma unroll
            for (int ch = 0; ch < 5; ++ch) {
                float s = 0.f;
#pragma unroll
                for (int k = 0; k < 7; ++k) s += gw.g[k] * wnd[ch][k];
                m[ch] = s;
            }
            float mu1 = m[0], mu2 = m[1];
            float mu1sq = mu1 * mu1, mu2sq = mu2 * mu2, mu12 = mu1 * mu2;
            float s1 = m[2] - mu1sq, s2 = m[3] - mu2sq, s12 = m[4] - mu12;
            float num = (2.f * mu12 + C1v) * (2.f * s12 + C2v);
            float den = (mu1sq + mu2sq + C1v) * (s1 + s2 + C2v);
            acc += num / den;
        }
    }

    // Block reduction: wave64 shuffle then LDS across 4 waves
#pragma unroll
    for (int off = 32; off > 0; off >>= 1)
        acc += __shfl_down(acc, off, 64);
    __shared__ float wsum[4];
    int lane = threadIdx.x & 63, wid = threadIdx.x >> 6;
    if (lane == 0) wsum[wid] = acc;
    __syncthreads();
    if (threadIdx.x == 0)
        partial[blockIdx.x] = wsum[0] + wsum[1] + wsum[2] + wsum[3];
}

// Stage 3: reduce partials -> 1 - mean
__global__ __launch_bounds__(256) void ssim_final(
        const float* __restrict__ partial, float* __restrict__ out) {
    float s = 0.f;
    for (int i = threadIdx.x; i < S2_BLOCKS; i += 256) s += partial[i];
#pragma unroll
    for (int off = 32; off > 0; off >>= 1)
        s += __shfl_down(s, off, 64);
    __shared__ float wsum[4];
    int lane = threadIdx.x & 63, wid = threadIdx.x >> 6;
    if (lane == 0) wsum[wid] = s;
    __syncthreads();
    if (threadIdx.x == 0) {
        float tot = wsum[0] + wsum[1] + wsum[2] + wsum[3];
        out[0] = 1.0f - tot / (float)NEL;
    }
}

extern "C" void kernel_launch(void* const* d_in, const int* in_sizes, int n_in,
                              void* d_out, int out_size, void* d_ws, size_t ws_size,
                              hipStream_t stream) {
    const float* p = (const float*)d_in[0];
    const float* t = (const float*)d_in[1];
    float* out = (float*)d_out;

    float* inter = (float*)d_ws;                       // 5 * NEL floats
    float* partial = inter + 5ul * NEL;                // S2_BLOCKS floats

    // Host-side Gaussian weights (sigma = 7/6), normalized
    G7 gw;
    {
        double s = 0.0, sig = 7.0 / 6.0;
        double g[7];
        for (int i = 0; i < 7; ++i) {
            double d = (double)i - 3.0;
            g[i] = exp(-d * d / (2.0 * sig * sig));
            s += g[i];
        }
        for (int i = 0; i < 7; ++i) gw.g[i] = (float)(g[i] / s);
    }

    dim3 g1(WW / TX, HH / TY, NB * DD);   // (5, 10, 320)
    dim3 b1(TX, TY);
    ssim_stage1<<<g1, b1, 0, stream>>>(p, t, inter, gw);

    ssim_stage2<<<S2_BLOCKS, 256, 0, stream>>>(inter, partial, gw);

    ssim_final<<<1, 256, 0, stream>>>(partial, out);
}

// Round 2
// 171.940 us; speedup vs baseline: 1.0469x; 1.0469x over previous
//
#include <hip/hip_runtime.h>
#include <math.h>

#define DD 160
#define HH 160
#define WW 160
#define NB 2
#define NEL (NB*DD*HH*WW)   // 8,192,000 voxels
#define TX 32
#define TY 16
#define ZC 32               // z-outputs per block
#define NCHUNK (DD/ZC)      // 5
#define GX (WW/TX)          // 5
#define GY (HH/TY)          // 10
#define NPART (GX*GY*NB*NCHUNK)  // 500 blocks

struct G7 { float g[7]; };

// Fully fused separable 3D SSIM:
//  - per z-slice: stage p,t halo tile in LDS -> x-conv (5 channels, products
//    formed per tap) -> y-conv to registers v[5]
//  - z-conv via 7-slot register ring: acc[j] = acc[j+1] + g[5-j]*v (shift+FMA
//    fused, slot6 reset to 0). Each output accumulates only from its first
//    slice (enters at slot 6 == 0), so no startup-pollution guards needed.
//  - SSIM map consumed in-register, block-reduced to one partial per block.
__global__ __launch_bounds__(512) void ssim_fused(
        const float* __restrict__ p, const float* __restrict__ t,
        float* __restrict__ partial, G7 gw) {
    const int tx = threadIdx.x;            // 0..31
    const int ty = threadIdx.y;            // 0..15
    const int x0 = blockIdx.x * TX;
    const int y0 = blockIdx.y * TY;
    const int n = blockIdx.z / NCHUNK;     // batch
    const int chunk = blockIdx.z % NCHUNK;
    const int zs = chunk * ZC;

    __shared__ float sp[TY + 6][TX + 6];
    __shared__ float st[TY + 6][TX + 6];
    __shared__ float c5[5][TY + 6][TX];

    float acc[5][7];
#pragma unroll
    for (int ch = 0; ch < 5; ++ch)
#pragma unroll
        for (int j = 0; j < 7; ++j) acc[ch][j] = 0.f;

    const float C1v = 1e-4f, C2v = 9e-4f;
    float ssum = 0.f;

    const size_t vol = (size_t)DD * HH * WW;
    const float* pvol = p + (size_t)n * vol;
    const float* tvol = t + (size_t)n * vol;

    for (int s = zs - 3; s < zs + ZC + 3; ++s) {
        float v[5];
        const bool valid = (s >= 0 && s < DD);   // block-uniform
        if (valid) {
            const float* pb = pvol + (size_t)s * (HH * WW);
            const float* tb = tvol + (size_t)s * (HH * WW);
            // ---- stage halo tile (zero pad outside slice) ----
#pragma unroll
            for (int r = ty; r < TY + 6; r += TY) {
                int gy = y0 + r - 3;
                bool yok = (unsigned)gy < (unsigned)HH;
#pragma unroll
                for (int cc = tx; cc < TX + 6; cc += TX) {
                    int gx = x0 + cc - 3;
                    float vp = 0.f, vt = 0.f;
                    if (yok && (unsigned)gx < (unsigned)WW) {
                        vp = pb[gy * WW + gx];
                        vt = tb[gy * WW + gx];
                    }
                    sp[r][cc] = vp;
                    st[r][cc] = vt;
                }
            }
            __syncthreads();
            // ---- x-conv, 5 channels (products per tap) ----
#pragma unroll
            for (int r = ty; r < TY + 6; r += TY) {
                float s0 = 0.f, s1 = 0.f, s2 = 0.f, s3 = 0.f, s4 = 0.f;
#pragma unroll
                for (int k = 0; k < 7; ++k) {
                    float wgt = gw.g[k];
                    float a = sp[r][tx + k], b = st[r][tx + k];
                    s0 += wgt * a;
                    s1 += wgt * b;
                    s2 += wgt * a * a;
                    s3 += wgt * b * b;
                    s4 += wgt * a * b;
                }
                c5[0][r][tx] = s0; c5[1][r][tx] = s1; c5[2][r][tx] = s2;
                c5[3][r][tx] = s3; c5[4][r][tx] = s4;
            }
            __syncthreads();
            // ---- y-conv -> v[5] ----
            float r0 = 0.f, r1 = 0.f, r2 = 0.f, r3 = 0.f, r4 = 0.f;
#pragma unroll
            for (int k = 0; k < 7; ++k) {
                float wgt = gw.g[k];
                r0 += wgt * c5[0][ty + k][tx];
                r1 += wgt * c5[1][ty + k][tx];
                r2 += wgt * c5[2][ty + k][tx];
                r3 += wgt * c5[3][ty + k][tx];
                r4 += wgt * c5[4][ty + k][tx];
            }
            v[0] = r0; v[1] = r1; v[2] = r2; v[3] = r3; v[4] = r4;
        } else {
#pragma unroll
            for (int ch = 0; ch < 5; ++ch) v[ch] = 0.f;
        }

        // ---- z ring: consume slot0 (output z=s-3), shift+add ----
        float cons[5];
#pragma unroll
        for (int ch = 0; ch < 5; ++ch) {
            cons[ch] = acc[ch][0] + gw.g[6] * v[ch];
#pragma unroll
            for (int j = 0; j < 6; ++j)
                acc[ch][j] = acc[ch][j + 1] + gw.g[5 - j] * v[ch];
            acc[ch][6] = 0.f;
        }
        if (s >= zs + 3) {   // output z = s-3 in [zs, zs+ZC)
            float mu1 = cons[0], mu2 = cons[1];
            float mu1sq = mu1 * mu1, mu2sq = mu2 * mu2, mu12 = mu1 * mu2;
            float s1 = cons[2] - mu1sq, s2 = cons[3] - mu2sq, s12 = cons[4] - mu12;
            float num = (2.f * mu12 + C1v) * (2.f * s12 + C2v);
            float den = (mu1sq + mu2sq + C1v) * (s1 + s2 + C2v);
            ssum += num * __builtin_amdgcn_rcpf(den);
        }
    }

    // ---- block reduction: wave shuffle then cross-wave LDS ----
#pragma unroll
    for (int off = 32; off > 0; off >>= 1)
        ssum += __shfl_down(ssum, off, 64);
    __shared__ float wsum[8];
    int tid = ty * TX + tx;
    int lane = tid & 63, wid = tid >> 6;
    if (lane == 0) wsum[wid] = ssum;
    __syncthreads();
    if (tid == 0) {
        float tot = 0.f;
#pragma unroll
        for (int w = 0; w < 8; ++w) tot += wsum[w];
        int bid = (blockIdx.z * GY + blockIdx.y) * GX + blockIdx.x;
        partial[bid] = tot;
    }
}

__global__ __launch_bounds__(256) void ssim_final(
        const float* __restrict__ partial, float* __restrict__ out) {
    float s = 0.f;
    for (int i = threadIdx.x; i < NPART; i += 256) s += partial[i];
#pragma unroll
    for (int off = 32; off > 0; off >>= 1)
        s += __shfl_down(s, off, 64);
    __shared__ float wsum[4];
    int lane = threadIdx.x & 63, wid = threadIdx.x >> 6;
    if (lane == 0) wsum[wid] = s;
    __syncthreads();
    if (threadIdx.x == 0) {
        float tot = wsum[0] + wsum[1] + wsum[2] + wsum[3];
        out[0] = 1.0f - tot / (float)NEL;
    }
}

extern "C" void kernel_launch(void* const* d_in, const int* in_sizes, int n_in,
                              void* d_out, int out_size, void* d_ws, size_t ws_size,
                              hipStream_t stream) {
    const float* p = (const float*)d_in[0];
    const float* t = (const float*)d_in[1];
    float* out = (float*)d_out;
    float* partial = (float*)d_ws;   // NPART floats

    G7 gw;
    {
        double s = 0.0, sig = 7.0 / 6.0;
        double g[7];
        for (int i = 0; i < 7; ++i) {
            double d = (double)i - 3.0;
            g[i] = exp(-d * d / (2.0 * sig * sig));
            s += g[i];
        }
        for (int i = 0; i < 7; ++i) gw.g[i] = (float)(g[i] / s);
    }

    dim3 grid(GX, GY, NB * NCHUNK);   // (5, 10, 10)
    dim3 block(TX, TY);               // 512 threads
    ssim_fused<<<grid, block, 0, stream>>>(p, t, partial, gw);
    ssim_final<<<1, 256, 0, stream>>>(partial, out);
}